// Round 7
// baseline (276.458 us; speedup 1.0000x reference)
//
#include <hip/hip_runtime.h>

// ---------------------------------------------------------------------------
// MLA attention, fp16 MFMA pipeline v7.  B=2, S=2048, D=1024, H=16, Dh=64, L=256
//
// Launches (6):
//   prep   : xh = f16(x)  +  Bt1=[Wq^T;Wl^T], Bt2=[Wk^T;Wv^T], Wot=Wo^T
//   GEMM1  : xh@Bt1 -> q' (=(xWq+bq)*0.125, f16) | lat          [r4 shape]
//   GEMM2  : lat@Bt2 -> k (RM) | vt[bh][d][s] (LDS-transposed)  [r4 shape]
//   attn   : split-KV x2, 128q/block, BARRIER-FREE: K and V^T fragments
//            loaded directly from global (L1/L2-resident), only P in LDS
//            (per-wave rows). Fixed-shift softmax p=exp(s-3).
//   combine: att = (O0+O1)/(l0+l1)  [r4, measured-good]
//   GEMM3  : att@Wot -> out (f32)   [r4, global_load_lds staging]
//
// MFMA 16x16x32 f16 layouts (HW-verified r2/r3):
//   A-frag: lane holds A[m=lane&15][k=quad*8+j]   B-frag: Bt[n=lane&15][k..]
//   C/D:    lane reg r holds C[row=quad*4+r][col=lane&15]
// ---------------------------------------------------------------------------

typedef _Float16 half8  __attribute__((ext_vector_type(8)));
typedef _Float16 half4  __attribute__((ext_vector_type(4)));
typedef float    floatx4 __attribute__((ext_vector_type(4)));

// ---------------- prep: convert x + all weight transposes ----------------
__global__ __launch_bounds__(256) void prep(
    const float* __restrict__ x,
    const float* __restrict__ Wq, const float* __restrict__ Wl,
    const float* __restrict__ Wk, const float* __restrict__ Wv,
    const float* __restrict__ Wo,
    _Float16* __restrict__ xh,
    _Float16* __restrict__ Bt1, _Float16* __restrict__ Bt2,
    _Float16* __restrict__ Wot)
{
    const int t = threadIdx.x;
    if (blockIdx.z == 5) {              // convert x: 1024 slots x 256 thr x 16
        size_t base = ((size_t)(blockIdx.y * 32 + blockIdx.x) * 256 + t) * 16;
#pragma unroll
        for (int it = 0; it < 4; ++it) {
            floatx4 v = *(const floatx4*)(x + base + it * 4);
            *(half4*)(xh + base + it * 4) = __builtin_convertvector(v, half4);
        }
        return;
    }
    const float* src; _Float16* dst; int K, N;
    switch (blockIdx.z) {
        case 0:  src = Wq; dst = Bt1;                 K = 1024; N = 1024; break;
        case 1:  src = Wl; dst = Bt1 + 1024 * 1024;   K = 1024; N = 256;  break;
        case 2:  src = Wk; dst = Bt2;                 K = 256;  N = 1024; break;
        case 3:  src = Wv; dst = Bt2 + 1024 * 256;    K = 256;  N = 1024; break;
        default: src = Wo; dst = Wot;                 K = 1024; N = 1024; break;
    }
    const int n0 = blockIdx.x * 32, k0 = blockIdx.y * 32;
    if (n0 >= N || k0 >= K) return;
    __shared__ _Float16 tile[32][33];
    const int tx = t & 31, ty = t >> 5;
#pragma unroll
    for (int i = 0; i < 4; ++i)
        tile[ty + 8 * i][tx] = (_Float16)src[(size_t)(k0 + ty + 8 * i) * N + n0 + tx];
    __syncthreads();
#pragma unroll
    for (int i = 0; i < 4; ++i)
        dst[(size_t)(n0 + ty + 8 * i) * K + k0 + tx] = tile[tx][ty + 8 * i];
}

// ---------------- fp16 MFMA GEMM, 128x64 tile, BK=32, 4 waves (64x32 each) --
// MODE 0: col<1024 -> q'=0.125*(c+bq) f16; col>=1024 -> lat f16 [*,256]
// MODE 1: col<1024 -> k f16 RM; col>=1024 -> vt[bh][d][s] via LDS transpose
// MODE 2: out f32 RM + bias
template <int MODE>
__global__ __launch_bounds__(256, 4) void gemm_fused(
    const _Float16* __restrict__ A, const _Float16* __restrict__ Bt,
    const float* __restrict__ bias0, const float* __restrict__ bias1,
    void* __restrict__ out0, void* __restrict__ out1,
    int N, int K)
{
    __shared__ _Float16 As[128 * 32];                 // 8 KB
    __shared__ _Float16 Bs[64 * 32];                  // 4 KB
    __shared__ _Float16 Tt[(MODE == 1) ? 64 * 136 : 1];
    const int t = threadIdx.x;
    const int lane = t & 63, w = t >> 6;
    const int quad = lane >> 4, low = lane & 15;
    const int row0 = blockIdx.y * 128, col0 = blockIdx.x * 64;
    const int wm = (w >> 1) * 64, wn = (w & 1) * 32;

    floatx4 acc[4][2];
    const floatx4 z4 = {0.f, 0.f, 0.f, 0.f};
#pragma unroll
    for (int i = 0; i < 4; ++i)
#pragma unroll
        for (int j = 0; j < 2; ++j) acc[i][j] = z4;

    const int srow = lane >> 2;          // 16 rows/chunk, 4 lanes per row
    const int scol = (lane & 3) * 8;     // 8-half col groups

    for (int k0 = 0; k0 < K; k0 += 32) {
        __syncthreads();
#pragma unroll
        for (int c = 0; c < 2; ++c) {      // A: 8 chunks of 16 rows
            const int chunk = w * 2 + c;
            const _Float16* g = A + (size_t)(row0 + chunk * 16 + srow) * K + k0 + scol;
            __builtin_amdgcn_global_load_lds(
                (const __attribute__((address_space(1))) void*)g,
                (__attribute__((address_space(3))) void*)(As + chunk * 512), 16, 0, 0);
        }
        {                                   // B: 4 chunks, wave w stages chunk w
            const _Float16* g = Bt + (size_t)(col0 + w * 16 + srow) * K + k0 + scol;
            __builtin_amdgcn_global_load_lds(
                (const __attribute__((address_space(1))) void*)g,
                (__attribute__((address_space(3))) void*)(Bs + w * 512), 16, 0, 0);
        }
        __syncthreads();

        half8 a[4], b[2];
#pragma unroll
        for (int i = 0; i < 4; ++i)
            a[i] = *(const half8*)(As + (wm + i * 16 + low) * 32 + quad * 8);
#pragma unroll
        for (int j = 0; j < 2; ++j)
            b[j] = *(const half8*)(Bs + (wn + j * 16 + low) * 32 + quad * 8);
#pragma unroll
        for (int i = 0; i < 4; ++i)
#pragma unroll
            for (int j = 0; j < 2; ++j)
                acc[i][j] = __builtin_amdgcn_mfma_f32_16x16x32_f16(a[i], b[j], acc[i][j], 0, 0, 0);
    }

    if (MODE == 1 && col0 >= 1024) {
        // vt epilogue: LDS transpose -> coalesced [bh][d][tok] half8 stores
        const int hh = (col0 - 1024) >> 6;
        const int bb = row0 >> 11;
        const int tok0 = row0 & 2047;
#pragma unroll
        for (int i = 0; i < 4; ++i)
#pragma unroll
            for (int j = 0; j < 2; ++j) {
                const int lc = wn + j * 16 + low;            // d within head
                float bv = bias1[hh * 64 + lc];
                half4 ph;
#pragma unroll
                for (int r = 0; r < 4; ++r) ph[r] = (_Float16)(acc[i][j][r] + bv);
                *(half4*)(&Tt[lc * 136 + wm + i * 16 + quad * 4]) = ph;
            }
        __syncthreads();
        _Float16* vb = (_Float16*)out1 + ((size_t)(bb * 16 + hh) * 64) * 2048;
#pragma unroll
        for (int it = 0; it < 4; ++it) {
            const int e = t + 256 * it;           // 1024 half8 groups
            const int d = e >> 4, tk = (e & 15) * 8;
            half8 val = *(const half8*)(&Tt[d * 136 + tk]);
            *(half8*)(vb + (size_t)d * 2048 + tok0 + tk) = val;
        }
        return;
    }

#pragma unroll
    for (int i = 0; i < 4; ++i) {
#pragma unroll
        for (int j = 0; j < 2; ++j) {
            const int col = col0 + wn + j * 16 + low;
            const int rbase = row0 + wm + i * 16 + quad * 4;
            if (MODE == 2) {
                const float bv = bias0[col];
#pragma unroll
                for (int r = 0; r < 4; ++r)
                    ((float*)out0)[(size_t)(rbase + r) * 1024 + col] = acc[i][j][r] + bv;
            } else if (col < 1024) {
                float bv = bias0[col];
#pragma unroll
                for (int r = 0; r < 4; ++r) {
                    float val = acc[i][j][r] + bv;
                    if (MODE == 0) val *= 0.125f;   // fold attention scale into q
                    ((_Float16*)out0)[(size_t)(rbase + r) * 1024 + col] = (_Float16)val;
                }
            } else {                               // MODE 0 lat region
                const int c2 = col - 1024;
                float bv = bias1[c2];
#pragma unroll
                for (int r = 0; r < 4; ++r)
                    ((_Float16*)out1)[(size_t)(rbase + r) * 256 + c2] =
                        (_Float16)(acc[i][j][r] + bv);
            }
        }
    }
}

// ---------------- flash attention v7: barrier-free, direct-global K/V ------
// Block = 128 queries x 1024 keys of one (b,h); blockIdx.z = KV split.
// K frags (A-op) and V^T frags (B-op) read straight from global (per-(b,h)
// slices are L1/L2-resident; every lane reads 16B contiguous). Only the
// P tile round-trips LDS, in per-wave rows -> ZERO __syncthreads in the loop:
// next tile's loads stay in flight across this tile's MFMAs (vmcnt pipeline).
__global__ __launch_bounds__(256, 4) void mla_attn(
    const _Float16* __restrict__ qp,  // [4096][1024], pre-scaled 0.125
    const _Float16* __restrict__ kk,  // [4096][1024]
    const _Float16* __restrict__ vt,  // [32][64][2048]
    _Float16* __restrict__ Op0, _Float16* __restrict__ Op1,
    float* __restrict__ lp)           // [2][32][2048]
{
    constexpr int S = 2048;
    __shared__ _Float16 Ps[128][76];   // P tile [i][j], per-wave rows, 19 KB

    const int t = threadIdx.x, lane = t & 63, w = t >> 6;
    const int quad = lane >> 4, low = lane & 15;
    const int q0 = blockIdx.x * 128;
    const int b = blockIdx.y >> 4, h = blockIdx.y & 15;
    const int split = blockIdx.z;

    // q B-frags: wave w owns queries q0+w*32 .. +31
    half8 qf[2][2];
#pragma unroll
    for (int ni = 0; ni < 2; ++ni)
#pragma unroll
        for (int ks = 0; ks < 2; ++ks)
            qf[ni][ks] = *(const half8*)(qp +
                (size_t)(b * S + q0 + w * 32 + ni * 16 + low) * 1024 +
                h * 64 + ks * 32 + quad * 8);

    floatx4 oa[2][4], ls[2];
    const floatx4 z4 = {0.f, 0.f, 0.f, 0.f};
#pragma unroll
    for (int mi = 0; mi < 2; ++mi) {
        ls[mi] = z4;
#pragma unroll
        for (int nd = 0; nd < 4; ++nd) oa[mi][nd] = z4;
    }

    const _Float16* kbase = kk + (size_t)(b * S) * 1024 + h * 64;
    const _Float16* vbase = vt + (size_t)(b * 16 + h) * 64 * 2048;

    const int jbeg = split * 1024, jend = jbeg + 1024;
    for (int j0 = jbeg; j0 < jend; j0 += 64) {
        // V^T frags for this tile, direct from global (used only in PV;
        // issued early so their latency hides under QK^T + exp)
        half8 vf[4][2];
#pragma unroll
        for (int nd = 0; nd < 4; ++nd)
#pragma unroll
            for (int ks = 0; ks < 2; ++ks)
                vf[nd][ks] = *(const half8*)(vbase +
                    (size_t)(nd * 16 + low) * 2048 + j0 + ks * 32 + quad * 8);

        // S^T = K q'^T per 16-row j-chunk; exp + pack immediately (low reg use)
#pragma unroll
        for (int mj = 0; mj < 4; ++mj) {
            half8 af0 = *(const half8*)(kbase +
                (size_t)(j0 + mj * 16 + low) * 1024 + quad * 8);
            half8 af1 = *(const half8*)(kbase +
                (size_t)(j0 + mj * 16 + low) * 1024 + 32 + quad * 8);
            const floatx4 i4 = {-3.f, -3.f, -3.f, -3.f};
            floatx4 s0 = i4, s1 = i4;
            s0 = __builtin_amdgcn_mfma_f32_16x16x32_f16(af0, qf[0][0], s0, 0, 0, 0);
            s0 = __builtin_amdgcn_mfma_f32_16x16x32_f16(af1, qf[0][1], s0, 0, 0, 0);
            s1 = __builtin_amdgcn_mfma_f32_16x16x32_f16(af0, qf[1][0], s1, 0, 0, 0);
            s1 = __builtin_amdgcn_mfma_f32_16x16x32_f16(af1, qf[1][1], s1, 0, 0, 0);
            floatx4 p0, p1;
#pragma unroll
            for (int r = 0; r < 4; ++r) { p0[r] = __expf(s0[r]); p1[r] = __expf(s1[r]); }
            ls[0] += p0;
            ls[1] += p1;
            half4 h0, h1;
#pragma unroll
            for (int r = 0; r < 4; ++r) { h0[r] = (_Float16)p0[r]; h1[r] = (_Float16)p1[r]; }
            *(half4*)(&Ps[w * 32 + low][mj * 16 + quad * 4]) = h0;
            *(half4*)(&Ps[w * 32 + 16 + low][mj * 16 + quad * 4]) = h1;
        }

        // O += P V  (same-wave P rows: DS RAW handled by lgkmcnt, no barrier)
#pragma unroll
        for (int ks = 0; ks < 2; ++ks) {
            half8 pf[2];
#pragma unroll
            for (int mi = 0; mi < 2; ++mi)
                pf[mi] = *(const half8*)(&Ps[w * 32 + mi * 16 + low][ks * 32 + quad * 8]);
#pragma unroll
            for (int mi = 0; mi < 2; ++mi)
#pragma unroll
                for (int nd = 0; nd < 4; ++nd)
                    oa[mi][nd] = __builtin_amdgcn_mfma_f32_16x16x32_f16(pf[mi], vf[nd][ks], oa[mi][nd], 0, 0, 0);
        }
    }

    // partial row-sums -> lp; partial O (unnormalized) -> Op
#pragma unroll
    for (int ni = 0; ni < 2; ++ni) {
        float l = ls[ni][0] + ls[ni][1] + ls[ni][2] + ls[ni][3];
        l += __shfl_xor(l, 16);
        l += __shfl_xor(l, 32);
        if (quad == 0)
            lp[split * 65536 + (b * 16 + h) * 2048 + q0 + w * 32 + ni * 16 + low] = l;
    }
    _Float16* op = split ? Op1 : Op0;
#pragma unroll
    for (int mi = 0; mi < 2; ++mi)
#pragma unroll
        for (int nd = 0; nd < 4; ++nd)
#pragma unroll
            for (int r = 0; r < 4; ++r)
                op[(size_t)(b * S + q0 + w * 32 + mi * 16 + quad * 4 + r) * 1024 +
                   h * 64 + nd * 16 + low] = (_Float16)oa[mi][nd][r];
}

// ---------------- combine: att = (O0+O1) / (l0+l1) ----------------
__global__ __launch_bounds__(256) void attn_combine(
    const _Float16* __restrict__ O0, const _Float16* __restrict__ O1,
    const float* __restrict__ lp, _Float16* __restrict__ att)
{
    size_t idx = ((size_t)blockIdx.x * 256 + threadIdx.x) * 8;
    int row = (int)(idx >> 10), c = (int)(idx & 1023);
    int b = row >> 11, qq = row & 2047, h = c >> 6;
    int li = (b * 16 + h) * 2048 + qq;
    float inv = 1.f / (lp[li] + lp[65536 + li]);
    half8 a = *(const half8*)(O0 + idx);
    half8 bb = *(const half8*)(O1 + idx);
    half8 o;
#pragma unroll
    for (int r = 0; r < 8; ++r)
        o[r] = (_Float16)(((float)a[r] + (float)bb[r]) * inv);
    *(half8*)(att + idx) = o;
}

extern "C" void kernel_launch(void* const* d_in, const int* in_sizes, int n_in,
                              void* d_out, int out_size, void* d_ws, size_t ws_size,
                              hipStream_t stream) {
    const float* x  = (const float*)d_in[0];
    const float* Wq = (const float*)d_in[1];
    const float* bq = (const float*)d_in[2];
    const float* Wl = (const float*)d_in[3];
    const float* bl = (const float*)d_in[4];
    const float* Wk = (const float*)d_in[5];
    const float* bk = (const float*)d_in[6];
    const float* Wv = (const float*)d_in[7];
    const float* bv = (const float*)d_in[8];
    const float* Wo = (const float*)d_in[9];
    const float* bo = (const float*)d_in[10];
    float* out = (float*)d_out;

    // workspace carve-up (halfs), ~49.9 MB
    _Float16* p   = (_Float16*)d_ws;
    _Float16* xh  = p; p += 4194304;   // x f16; dead after GEMM1 -> Opart[1]
    _Float16* qh  = p; p += 4194304;   // q' (pre-scaled by 0.125)
    _Float16* kh  = p; p += 4194304;   // k; dead after attn -> combined att
    _Float16* vtb = p; p += 4194304;   // vt [32][64][2048]
    _Float16* ah  = p; p += 4194304;   // Opart[0]
    _Float16* lat = p; p += 1048576;   // lat; dead after GEMM2 -> lp (f32)
    _Float16* Bt1 = p; p += 1310720;
    _Float16* Bt2 = p; p += 524288;
    _Float16* Wot = p; p += 1048576;

    prep<<<dim3(32, 32, 6), 256, 0, stream>>>(x, Wq, Wl, Wk, Wv, Wo, xh, Bt1, Bt2, Wot);

    gemm_fused<0><<<dim3(20, 32), 256, 0, stream>>>(
        xh, Bt1, bq, bl, qh, lat, 1280, 1024);
    gemm_fused<1><<<dim3(32, 32), 256, 0, stream>>>(
        lat, Bt2, bk, bv, kh, vtb, 2048, 256);
    mla_attn<<<dim3(16, 32, 2), 256, 0, stream>>>(qh, kh, vtb, ah, xh, (float*)lat);
    attn_combine<<<2048, 256, 0, stream>>>(ah, xh, (const float*)lat, kh);
    gemm_fused<2><<<dim3(16, 32), 256, 0, stream>>>(
        kh, Wot, bo, nullptr, out, nullptr, 1024, 1024);
}

// Round 8
// 210.676 us; speedup vs baseline: 1.3122x; 1.3122x over previous
//
#include <hip/hip_runtime.h>

// ---------------------------------------------------------------------------
// MLA attention, fp16 MFMA pipeline v8.  B=2, S=2048, D=1024, H=16, Dh=64, L=256
//
// Launches (6):
//   prep   : xh = f16(x) [swz] + Bt1=[Wq^T;Wl^T], Bt2=[Wk^T;Wv^T], Wot=Wo^T [swz]
//   GEMM1  : xh@Bt1 -> q' (0.125*(xWq+bq), linear) | lat [swz]
//   GEMM2  : lat@Bt2 -> k (linear) | vt[bh][d][s] (linear, LDS-transposed)
//   attn   : r6-measured: split-KV x2, 256q/block (64q/wave), fixed-shift
//            softmax p=exp(s-3); partial O (f16) + l (f32) plain sums
//   combine: att = (O0+O1)/(l0+l1)  [swz]
//   GEMM3  : att@Wot -> out (f32)
//
// SWIZZLE (new): GEMM LDS frag reads at 64B row stride are 8-way bank
// conflicted (m98/m136). global_load_lds forbids padding (m104), so inputs
// are stored with 16B groups XOR-permuted per row: group g of row r lives at
// g ^ m(r), m(r)=(r^(r>>2))&3.  Staging copies linearly; frag reads use
// (quad*8) ^ swz with swz=((low^(low>>2))&3)<<3  ->  2-way (free) banks.
//
// MFMA 16x16x32 f16 layouts (HW-verified r2/r3):
//   A-frag: lane holds A[m=lane&15][k=quad*8+j]   B-frag: Bt[n=lane&15][k..]
//   C/D:    lane reg r holds C[row=quad*4+r][col=lane&15]
// ---------------------------------------------------------------------------

typedef _Float16 half8  __attribute__((ext_vector_type(8)));
typedef _Float16 half4  __attribute__((ext_vector_type(4)));
typedef float    floatx4 __attribute__((ext_vector_type(4)));

__device__ __forceinline__ int swz_mask(int row) { return ((row ^ (row >> 2)) & 3) << 3; }

// ---------------- prep: convert x (swz) + weight transposes (swz) ----------
__global__ __launch_bounds__(256) void prep(
    const float* __restrict__ x,
    const float* __restrict__ Wq, const float* __restrict__ Wl,
    const float* __restrict__ Wk, const float* __restrict__ Wv,
    const float* __restrict__ Wo,
    _Float16* __restrict__ xh,
    _Float16* __restrict__ Bt1, _Float16* __restrict__ Bt2,
    _Float16* __restrict__ Wot)
{
    const int t = threadIdx.x;
    if (blockIdx.z == 5) {              // convert x, swizzled within 1024-rows
        size_t gbase = ((size_t)(blockIdx.y * 32 + blockIdx.x) * 256 + t) * 16;
        const int row = (int)(gbase >> 10);
        const int m = swz_mask(row);
        const size_t rowbase = (size_t)row << 10;
        const int h0 = (int)(gbase & 1023);
#pragma unroll
        for (int it = 0; it < 4; ++it) {
            floatx4 v = *(const floatx4*)(x + gbase + it * 4);
            *(half4*)(xh + rowbase + ((h0 + it * 4) ^ m)) =
                __builtin_convertvector(v, half4);
        }
        return;
    }
    const float* src; _Float16* dst; int K, N;
    switch (blockIdx.z) {
        case 0:  src = Wq; dst = Bt1;                 K = 1024; N = 1024; break;
        case 1:  src = Wl; dst = Bt1 + 1024 * 1024;   K = 1024; N = 256;  break;
        case 2:  src = Wk; dst = Bt2;                 K = 256;  N = 1024; break;
        case 3:  src = Wv; dst = Bt2 + 1024 * 256;    K = 256;  N = 1024; break;
        default: src = Wo; dst = Wot;                 K = 1024; N = 1024; break;
    }
    const int n0 = blockIdx.x * 32, k0 = blockIdx.y * 32;
    if (n0 >= N || k0 >= K) return;
    __shared__ _Float16 tile[32][33];
    const int tx = t & 31, ty = t >> 5;
#pragma unroll
    for (int i = 0; i < 4; ++i)
        tile[ty + 8 * i][tx] = (_Float16)src[(size_t)(k0 + ty + 8 * i) * N + n0 + tx];
    __syncthreads();
#pragma unroll
    for (int i = 0; i < 4; ++i) {
        const int n = n0 + ty + 8 * i;
        dst[(size_t)n * K + ((k0 + tx) ^ swz_mask(n))] = tile[tx][ty + 8 * i];
    }
}

// ---------------- fp16 MFMA GEMM, 128x64 tile, BK=32, 4 waves (64x32 each) --
// Inputs A,Bt are SWIZZLED; frag reads un-swizzle. Staging is linear copy.
// MODE 0: col<1024 -> q'=0.125*(c+bq) f16 LINEAR; col>=1024 -> lat f16 SWZ
// MODE 1: col<1024 -> k f16 LINEAR; col>=1024 -> vt[bh][d][s] LINEAR
// MODE 2: out f32 + bias
template <int MODE>
__global__ __launch_bounds__(256, 4) void gemm_fused(
    const _Float16* __restrict__ A, const _Float16* __restrict__ Bt,
    const float* __restrict__ bias0, const float* __restrict__ bias1,
    void* __restrict__ out0, void* __restrict__ out1,
    int N, int K)
{
    __shared__ _Float16 As[128 * 32];                 // 8 KB
    __shared__ _Float16 Bs[64 * 32];                  // 4 KB
    __shared__ _Float16 Tt[(MODE == 1) ? 64 * 136 : 1];
    const int t = threadIdx.x;
    const int lane = t & 63, w = t >> 6;
    const int quad = lane >> 4, low = lane & 15;
    const int row0 = blockIdx.y * 128, col0 = blockIdx.x * 64;
    const int wm = (w >> 1) * 64, wn = (w & 1) * 32;
    const int swz = ((low ^ (low >> 2)) & 3) << 3;    // un-swizzle for frag reads

    floatx4 acc[4][2];
    const floatx4 z4 = {0.f, 0.f, 0.f, 0.f};
#pragma unroll
    for (int i = 0; i < 4; ++i)
#pragma unroll
        for (int j = 0; j < 2; ++j) acc[i][j] = z4;

    const int srow = lane >> 2;          // 16 rows/chunk, 4 lanes per row
    const int scol = (lane & 3) * 8;     // 8-half col groups

    for (int k0 = 0; k0 < K; k0 += 32) {
        __syncthreads();
#pragma unroll
        for (int c = 0; c < 2; ++c) {      // A: 8 chunks of 16 rows
            const int chunk = w * 2 + c;
            const _Float16* g = A + (size_t)(row0 + chunk * 16 + srow) * K + k0 + scol;
            __builtin_amdgcn_global_load_lds(
                (const __attribute__((address_space(1))) void*)g,
                (__attribute__((address_space(3))) void*)(As + chunk * 512), 16, 0, 0);
        }
        {                                   // B: 4 chunks, wave w stages chunk w
            const _Float16* g = Bt + (size_t)(col0 + w * 16 + srow) * K + k0 + scol;
            __builtin_amdgcn_global_load_lds(
                (const __attribute__((address_space(1))) void*)g,
                (__attribute__((address_space(3))) void*)(Bs + w * 512), 16, 0, 0);
        }
        __syncthreads();

        half8 a[4], b[2];
#pragma unroll
        for (int i = 0; i < 4; ++i)
            a[i] = *(const half8*)(As + (wm + i * 16 + low) * 32 + ((quad * 8) ^ swz));
#pragma unroll
        for (int j = 0; j < 2; ++j)
            b[j] = *(const half8*)(Bs + (wn + j * 16 + low) * 32 + ((quad * 8) ^ swz));
#pragma unroll
        for (int i = 0; i < 4; ++i)
#pragma unroll
            for (int j = 0; j < 2; ++j)
                acc[i][j] = __builtin_amdgcn_mfma_f32_16x16x32_f16(a[i], b[j], acc[i][j], 0, 0, 0);
    }

    if (MODE == 1 && col0 >= 1024) {
        // vt epilogue: LDS transpose -> coalesced [bh][d][tok] half8 stores
        const int hh = (col0 - 1024) >> 6;
        const int bb = row0 >> 11;
        const int tok0 = row0 & 2047;
#pragma unroll
        for (int i = 0; i < 4; ++i)
#pragma unroll
            for (int j = 0; j < 2; ++j) {
                const int lc = wn + j * 16 + low;            // d within head
                float bv = bias1[hh * 64 + lc];
                half4 ph;
#pragma unroll
                for (int r = 0; r < 4; ++r) ph[r] = (_Float16)(acc[i][j][r] + bv);
                *(half4*)(&Tt[lc * 136 + wm + i * 16 + quad * 4]) = ph;
            }
        __syncthreads();
        _Float16* vb = (_Float16*)out1 + ((size_t)(bb * 16 + hh) * 64) * 2048;
#pragma unroll
        for (int it = 0; it < 4; ++it) {
            const int e = t + 256 * it;           // 1024 half8 groups
            const int d = e >> 4, tk = (e & 15) * 8;
            half8 val = *(const half8*)(&Tt[d * 136 + tk]);
            *(half8*)(vb + (size_t)d * 2048 + tok0 + tk) = val;
        }
        return;
    }

#pragma unroll
    for (int i = 0; i < 4; ++i) {
#pragma unroll
        for (int j = 0; j < 2; ++j) {
            const int col = col0 + wn + j * 16 + low;
            const int rbase = row0 + wm + i * 16 + quad * 4;
            if (MODE == 2) {
                const float bv = bias0[col];
#pragma unroll
                for (int r = 0; r < 4; ++r)
                    ((float*)out0)[(size_t)(rbase + r) * 1024 + col] = acc[i][j][r] + bv;
            } else if (col < 1024) {
                float bv = bias0[col];
#pragma unroll
                for (int r = 0; r < 4; ++r) {
                    float val = acc[i][j][r] + bv;
                    if (MODE == 0) val *= 0.125f;   // fold attention scale into q
                    ((_Float16*)out0)[(size_t)(rbase + r) * 1024 + col] = (_Float16)val;
                }
            } else {                               // MODE 0 lat region (SWIZZLED)
                const int c2 = col - 1024;
                float bv = bias1[c2];
#pragma unroll
                for (int r = 0; r < 4; ++r) {
                    const int row = rbase + r;
                    ((_Float16*)out1)[(size_t)row * 256 + (c2 ^ swz_mask(row))] =
                        (_Float16)(acc[i][j][r] + bv);
                }
            }
        }
    }
}

// ---------------- flash attention (r6-measured): split-KV, 64 q per wave ----
__global__ __launch_bounds__(256, 2) void mla_attn(
    const _Float16* __restrict__ qp,  // [4096][1024], pre-scaled 0.125, LINEAR
    const _Float16* __restrict__ kk,  // [4096][1024], LINEAR
    const _Float16* __restrict__ vt,  // [32][64][2048], LINEAR
    _Float16* __restrict__ Op0, _Float16* __restrict__ Op1,
    float* __restrict__ lp)           // [2][32][2048]
{
    constexpr int S = 2048;
    __shared__ _Float16 Ks[64][76];    // K tile   [j][d]   9.5 KB
    __shared__ _Float16 Vs[64][76];    // V^T tile [d][j]   9.5 KB
    __shared__ _Float16 Ps[256][76];   // P tile   [i][j]  38.0 KB

    const int t = threadIdx.x, lane = t & 63, w = t >> 6;
    const int quad = lane >> 4, low = lane & 15;
    const int q0 = blockIdx.x * 256;
    const int b = blockIdx.y >> 4, h = blockIdx.y & 15;
    const int split = blockIdx.z;

    half8 qf[4][2];
#pragma unroll
    for (int ni = 0; ni < 4; ++ni)
#pragma unroll
        for (int ks = 0; ks < 2; ++ks)
            qf[ni][ks] = *(const half8*)(qp +
                (size_t)(b * S + q0 + w * 64 + ni * 16 + low) * 1024 +
                h * 64 + ks * 32 + quad * 8);

    floatx4 oa[4][4], ls[4];
    const floatx4 z4 = {0.f, 0.f, 0.f, 0.f};
#pragma unroll
    for (int mi = 0; mi < 4; ++mi) {
        ls[mi] = z4;
#pragma unroll
        for (int nd = 0; nd < 4; ++nd) oa[mi][nd] = z4;
    }

    const _Float16* kbase = kk + (size_t)(b * S) * 1024 + h * 64;
    const _Float16* vbase = vt + (size_t)(b * 16 + h) * 64 * 2048;

    const int jbeg = split * 1024, jend = jbeg + 1024;
    for (int j0 = jbeg; j0 < jend; j0 += 64) {
        __syncthreads();
#pragma unroll
        for (int p = 0; p < 2; ++p) {
            int c = p * 256 + t;
            int r = c >> 3, o8 = (c & 7) * 8;
            *(half8*)(&Ks[r][o8]) = *(const half8*)(kbase + (size_t)(j0 + r) * 1024 + o8);
            *(half8*)(&Vs[r][o8]) = *(const half8*)(vbase + (size_t)r * 2048 + j0 + o8);
        }
        __syncthreads();

        floatx4 s[4][4];
        const floatx4 i4 = {-3.f, -3.f, -3.f, -3.f};
#pragma unroll
        for (int mj = 0; mj < 4; ++mj)
#pragma unroll
            for (int ni = 0; ni < 4; ++ni) s[mj][ni] = i4;
#pragma unroll
        for (int ks = 0; ks < 2; ++ks) {
            half8 af[4];
#pragma unroll
            for (int mj = 0; mj < 4; ++mj)
                af[mj] = *(const half8*)(&Ks[mj * 16 + low][ks * 32 + quad * 8]);
#pragma unroll
            for (int mj = 0; mj < 4; ++mj)
#pragma unroll
                for (int ni = 0; ni < 4; ++ni)
                    s[mj][ni] = __builtin_amdgcn_mfma_f32_16x16x32_f16(af[mj], qf[ni][ks], s[mj][ni], 0, 0, 0);
        }

#pragma unroll
        for (int mj = 0; mj < 4; ++mj)
#pragma unroll
            for (int ni = 0; ni < 4; ++ni) {
                floatx4 pv;
#pragma unroll
                for (int r = 0; r < 4; ++r) pv[r] = __expf(s[mj][ni][r]);
                ls[ni] += pv;
                half4 ph;
#pragma unroll
                for (int r = 0; r < 4; ++r) ph[r] = (_Float16)pv[r];
                *(half4*)(&Ps[w * 64 + ni * 16 + low][mj * 16 + quad * 4]) = ph;
            }

#pragma unroll
        for (int ks = 0; ks < 2; ++ks) {
            half8 pf[4], vf[4];
#pragma unroll
            for (int mi = 0; mi < 4; ++mi)
                pf[mi] = *(const half8*)(&Ps[w * 64 + mi * 16 + low][ks * 32 + quad * 8]);
#pragma unroll
            for (int nd = 0; nd < 4; ++nd)
                vf[nd] = *(const half8*)(&Vs[nd * 16 + low][ks * 32 + quad * 8]);
#pragma unroll
            for (int mi = 0; mi < 4; ++mi)
#pragma unroll
                for (int nd = 0; nd < 4; ++nd)
                    oa[mi][nd] = __builtin_amdgcn_mfma_f32_16x16x32_f16(pf[mi], vf[nd], oa[mi][nd], 0, 0, 0);
        }
    }

#pragma unroll
    for (int ni = 0; ni < 4; ++ni) {
        float l = ls[ni][0] + ls[ni][1] + ls[ni][2] + ls[ni][3];
        l += __shfl_xor(l, 16);
        l += __shfl_xor(l, 32);
        if (quad == 0)
            lp[split * 65536 + (b * 16 + h) * 2048 + q0 + w * 64 + ni * 16 + low] = l;
    }
    _Float16* op = split ? Op1 : Op0;
#pragma unroll
    for (int mi = 0; mi < 4; ++mi)
#pragma unroll
        for (int nd = 0; nd < 4; ++nd)
#pragma unroll
            for (int r = 0; r < 4; ++r)
                op[(size_t)(b * S + q0 + w * 64 + mi * 16 + quad * 4 + r) * 1024 +
                   h * 64 + nd * 16 + low] = (_Float16)oa[mi][nd][r];
}

// ---------------- combine: att = (O0+O1)/(l0+l1), SWIZZLED output ----------
__global__ __launch_bounds__(256) void attn_combine(
    const _Float16* __restrict__ O0, const _Float16* __restrict__ O1,
    const float* __restrict__ lp, _Float16* __restrict__ att)
{
    size_t idx = ((size_t)blockIdx.x * 256 + threadIdx.x) * 8;
    int row = (int)(idx >> 10), c = (int)(idx & 1023);
    int b = row >> 11, qq = row & 2047, h = c >> 6;
    int li = (b * 16 + h) * 2048 + qq;
    float inv = 1.f / (lp[li] + lp[65536 + li]);
    half8 a = *(const half8*)(O0 + idx);
    half8 bb = *(const half8*)(O1 + idx);
    half8 o;
#pragma unroll
    for (int r = 0; r < 8; ++r)
        o[r] = (_Float16)(((float)a[r] + (float)bb[r]) * inv);
    *(half8*)(att + ((size_t)row << 10) + (c ^ swz_mask(row))) = o;
}

extern "C" void kernel_launch(void* const* d_in, const int* in_sizes, int n_in,
                              void* d_out, int out_size, void* d_ws, size_t ws_size,
                              hipStream_t stream) {
    const float* x  = (const float*)d_in[0];
    const float* Wq = (const float*)d_in[1];
    const float* bq = (const float*)d_in[2];
    const float* Wl = (const float*)d_in[3];
    const float* bl = (const float*)d_in[4];
    const float* Wk = (const float*)d_in[5];
    const float* bk = (const float*)d_in[6];
    const float* Wv = (const float*)d_in[7];
    const float* bv = (const float*)d_in[8];
    const float* Wo = (const float*)d_in[9];
    const float* bo = (const float*)d_in[10];
    float* out = (float*)d_out;

    // workspace carve-up (halfs), ~49.9 MB
    _Float16* p   = (_Float16*)d_ws;
    _Float16* xh  = p; p += 4194304;   // x f16 (swz); dead after GEMM1 -> Opart[1]
    _Float16* qh  = p; p += 4194304;   // q' (pre-scaled, linear)
    _Float16* kh  = p; p += 4194304;   // k (linear); dead after attn -> att (swz)
    _Float16* vtb = p; p += 4194304;   // vt [32][64][2048] (linear)
    _Float16* ah  = p; p += 4194304;   // Opart[0]
    _Float16* lat = p; p += 1048576;   // lat (swz); dead after GEMM2 -> lp (f32)
    _Float16* Bt1 = p; p += 1310720;   // swz
    _Float16* Bt2 = p; p += 524288;    // swz
    _Float16* Wot = p; p += 1048576;   // swz

    prep<<<dim3(32, 32, 6), 256, 0, stream>>>(x, Wq, Wl, Wk, Wv, Wo, xh, Bt1, Bt2, Wot);

    gemm_fused<0><<<dim3(20, 32), 256, 0, stream>>>(
        xh, Bt1, bq, bl, qh, lat, 1280, 1024);
    gemm_fused<1><<<dim3(32, 32), 256, 0, stream>>>(
        lat, Bt2, bk, bv, kh, vtb, 2048, 256);
    mla_attn<<<dim3(8, 32, 2), 256, 0, stream>>>(qh, kh, vtb, ah, xh, (float*)lat);
    attn_combine<<<2048, 256, 0, stream>>>(ah, xh, (const float*)lat, kh);
    gemm_fused<2><<<dim3(16, 32), 256, 0, stream>>>(
        kh, Wot, bo, nullptr, out, nullptr, 1024, 1024);
}

// Round 9
// 206.557 us; speedup vs baseline: 1.3384x; 1.0199x over previous
//
#include <hip/hip_runtime.h>

// ---------------------------------------------------------------------------
// MLA attention, fp16 MFMA pipeline v9.  B=2, S=2048, D=1024, H=16, Dh=64, L=256
//
// Launches (6):
//   prep   : xh = f16(x) + Bt1=[Wq^T;Wl^T], Bt2=[Wk^T;Wv^T], Wot=Wo^T (linear)
//   GEMM1  : xh@Bt1 -> q' (0.125*(xWq+bq)) | lat          [BK=64, no occ bound]
//   GEMM2  : lat@Bt2 -> k | vt[bh][d][s]                  [BK=64]
//   attn   : r6-measured verbatim: split-KV x2, 256q/block, fixed-shift softmax
//   combine: att = (O0+O1)/(l0+l1)                        [r4 verbatim]
//   GEMM3  : att@Wot -> out (f32)                         [BK=64]
//
// GEMM v9: BK=64 halves the barrier count (each __syncthreads drains vmcnt,
// ~300 cyc, m135). No forced launch_bounds min-occupancy (spill-cliff risk).
// XOR-slot staging keeps frag reads bank-balanced WITHOUT touching global
// layouts: global_load_lds lane fetches 16B group (lane&7)^(row&7); frag
// reads use slot ((4*kk+quad)^(low&7)) -> every bank serves exactly 8 dwords
// per ds_read_b128 (uniform). Global arrays stay LINEAR (producers simple).
//
// MFMA 16x16x32 f16 layouts (HW-verified r2/r3):
//   A-frag: lane holds A[m=lane&15][k=quad*8+j]   B-frag: Bt[n=lane&15][k..]
//   C/D:    lane reg r holds C[row=quad*4+r][col=lane&15]
// ---------------------------------------------------------------------------

typedef _Float16 half8  __attribute__((ext_vector_type(8)));
typedef _Float16 half4  __attribute__((ext_vector_type(4)));
typedef float    floatx4 __attribute__((ext_vector_type(4)));

// ---------------- prep: convert x + all weight transposes (linear) ---------
__global__ __launch_bounds__(256) void prep(
    const float* __restrict__ x,
    const float* __restrict__ Wq, const float* __restrict__ Wl,
    const float* __restrict__ Wk, const float* __restrict__ Wv,
    const float* __restrict__ Wo,
    _Float16* __restrict__ xh,
    _Float16* __restrict__ Bt1, _Float16* __restrict__ Bt2,
    _Float16* __restrict__ Wot)
{
    const int t = threadIdx.x;
    if (blockIdx.z == 5) {              // convert x: 1024 slots x 256 thr x 16
        size_t base = ((size_t)(blockIdx.y * 32 + blockIdx.x) * 256 + t) * 16;
#pragma unroll
        for (int it = 0; it < 4; ++it) {
            floatx4 v = *(const floatx4*)(x + base + it * 4);
            *(half4*)(xh + base + it * 4) = __builtin_convertvector(v, half4);
        }
        return;
    }
    const float* src; _Float16* dst; int K, N;
    switch (blockIdx.z) {
        case 0:  src = Wq; dst = Bt1;                 K = 1024; N = 1024; break;
        case 1:  src = Wl; dst = Bt1 + 1024 * 1024;   K = 1024; N = 256;  break;
        case 2:  src = Wk; dst = Bt2;                 K = 256;  N = 1024; break;
        case 3:  src = Wv; dst = Bt2 + 1024 * 256;    K = 256;  N = 1024; break;
        default: src = Wo; dst = Wot;                 K = 1024; N = 1024; break;
    }
    const int n0 = blockIdx.x * 32, k0 = blockIdx.y * 32;
    if (n0 >= N || k0 >= K) return;
    __shared__ _Float16 tile[32][33];
    const int tx = t & 31, ty = t >> 5;
#pragma unroll
    for (int i = 0; i < 4; ++i)
        tile[ty + 8 * i][tx] = (_Float16)src[(size_t)(k0 + ty + 8 * i) * N + n0 + tx];
    __syncthreads();
#pragma unroll
    for (int i = 0; i < 4; ++i)
        dst[(size_t)(n0 + ty + 8 * i) * K + k0 + tx] = tile[tx][ty + 8 * i];
}

// ---------------- fp16 MFMA GEMM, 128x64 tile, BK=64, 4 waves (64x32 each) --
// MODE 0: col<1024 -> q'=0.125*(c+bq) f16; col>=1024 -> lat f16 [*,256]
// MODE 1: col<1024 -> k f16 RM; col>=1024 -> vt[bh][d][s] via LDS transpose
// MODE 2: out f32 RM + bias
template <int MODE>
__global__ __launch_bounds__(256) void gemm_fused(
    const _Float16* __restrict__ A, const _Float16* __restrict__ Bt,
    const float* __restrict__ bias0, const float* __restrict__ bias1,
    void* __restrict__ out0, void* __restrict__ out1,
    int N, int K)
{
    __shared__ _Float16 As[128 * 64];                 // 16 KB
    __shared__ _Float16 Bs[64 * 64];                  // 8 KB
    __shared__ _Float16 Tt[(MODE == 1) ? 64 * 136 : 1];
    const int t = threadIdx.x;
    const int lane = t & 63, w = t >> 6;
    const int quad = lane >> 4, low = lane & 15;
    const int row0 = blockIdx.y * 128, col0 = blockIdx.x * 64;
    const int wm = (w >> 1) * 64, wn = (w & 1) * 32;

    floatx4 acc[4][2];
    const floatx4 z4 = {0.f, 0.f, 0.f, 0.f};
#pragma unroll
    for (int i = 0; i < 4; ++i)
#pragma unroll
        for (int j = 0; j < 2; ++j) acc[i][j] = z4;

    // BK=64 staging: one inst = 8 rows x 8 slots of 16B. Lane (srow8, sslot).
    // Lane fetches global group sslot^(row&7) so LDS slot s holds group
    // s^(row&7): frag readers un-permute with the same XOR.
    const int srow8 = lane >> 3;
    const int sslot = lane & 7;
    const int fswz = (low & 7);          // frag-read XOR term

    for (int k0 = 0; k0 < K; k0 += 64) {
        __syncthreads();
#pragma unroll
        for (int c = 0; c < 4; ++c) {      // A: 16 chunks of 8 rows, 4 per wave
            const int chunk = w * 4 + c;
            const int row = chunk * 8 + srow8;
            const int g = sslot ^ (row & 7);
            const _Float16* gp = A + (size_t)(row0 + row) * K + k0 + g * 8;
            __builtin_amdgcn_global_load_lds(
                (const __attribute__((address_space(1))) void*)gp,
                (__attribute__((address_space(3))) void*)(As + chunk * 512), 16, 0, 0);
        }
#pragma unroll
        for (int c = 0; c < 2; ++c) {      // B: 8 chunks of 8 rows, 2 per wave
            const int chunk = w * 2 + c;
            const int row = chunk * 8 + srow8;
            const int g = sslot ^ (row & 7);
            const _Float16* gp = Bt + (size_t)(col0 + row) * K + k0 + g * 8;
            __builtin_amdgcn_global_load_lds(
                (const __attribute__((address_space(1))) void*)gp,
                (__attribute__((address_space(3))) void*)(Bs + chunk * 512), 16, 0, 0);
        }
        __syncthreads();

#pragma unroll
        for (int kk = 0; kk < 2; ++kk) {
            const int slot = ((4 * kk + quad) ^ fswz) << 3;
            half8 a[4], b[2];
#pragma unroll
            for (int i = 0; i < 4; ++i)
                a[i] = *(const half8*)(As + (wm + i * 16 + low) * 64 + slot);
#pragma unroll
            for (int j = 0; j < 2; ++j)
                b[j] = *(const half8*)(Bs + (wn + j * 16 + low) * 64 + slot);
#pragma unroll
            for (int i = 0; i < 4; ++i)
#pragma unroll
                for (int j = 0; j < 2; ++j)
                    acc[i][j] = __builtin_amdgcn_mfma_f32_16x16x32_f16(a[i], b[j], acc[i][j], 0, 0, 0);
        }
    }

    if (MODE == 1 && col0 >= 1024) {
        // vt epilogue: LDS transpose -> coalesced [bh][d][tok] half8 stores
        const int hh = (col0 - 1024) >> 6;
        const int bb = row0 >> 11;
        const int tok0 = row0 & 2047;
#pragma unroll
        for (int i = 0; i < 4; ++i)
#pragma unroll
            for (int j = 0; j < 2; ++j) {
                const int lc = wn + j * 16 + low;            // d within head
                float bv = bias1[hh * 64 + lc];
                half4 ph;
#pragma unroll
                for (int r = 0; r < 4; ++r) ph[r] = (_Float16)(acc[i][j][r] + bv);
                *(half4*)(&Tt[lc * 136 + wm + i * 16 + quad * 4]) = ph;
            }
        __syncthreads();
        _Float16* vb = (_Float16*)out1 + ((size_t)(bb * 16 + hh) * 64) * 2048;
#pragma unroll
        for (int it = 0; it < 4; ++it) {
            const int e = t + 256 * it;           // 1024 half8 groups
            const int d = e >> 4, tk = (e & 15) * 8;
            half8 val = *(const half8*)(&Tt[d * 136 + tk]);
            *(half8*)(vb + (size_t)d * 2048 + tok0 + tk) = val;
        }
        return;
    }

#pragma unroll
    for (int i = 0; i < 4; ++i) {
#pragma unroll
        for (int j = 0; j < 2; ++j) {
            const int col = col0 + wn + j * 16 + low;
            const int rbase = row0 + wm + i * 16 + quad * 4;
            if (MODE == 2) {
                const float bv = bias0[col];
#pragma unroll
                for (int r = 0; r < 4; ++r)
                    ((float*)out0)[(size_t)(rbase + r) * 1024 + col] = acc[i][j][r] + bv;
            } else if (col < 1024) {
                float bv = bias0[col];
#pragma unroll
                for (int r = 0; r < 4; ++r) {
                    float val = acc[i][j][r] + bv;
                    if (MODE == 0) val *= 0.125f;   // fold attention scale into q
                    ((_Float16*)out0)[(size_t)(rbase + r) * 1024 + col] = (_Float16)val;
                }
            } else {                               // MODE 0 lat region
                const int c2 = col - 1024;
                float bv = bias1[c2];
#pragma unroll
                for (int r = 0; r < 4; ++r)
                    ((_Float16*)out1)[(size_t)(rbase + r) * 256 + c2] =
                        (_Float16)(acc[i][j][r] + bv);
            }
        }
    }
}

// ---------------- flash attention (r6-measured): split-KV, 64 q per wave ----
__global__ __launch_bounds__(256, 2) void mla_attn(
    const _Float16* __restrict__ qp,  // [4096][1024], pre-scaled 0.125
    const _Float16* __restrict__ kk,  // [4096][1024]
    const _Float16* __restrict__ vt,  // [32][64][2048]
    _Float16* __restrict__ Op0, _Float16* __restrict__ Op1,
    float* __restrict__ lp)           // [2][32][2048]
{
    constexpr int S = 2048;
    __shared__ _Float16 Ks[64][76];    // K tile   [j][d]   9.5 KB
    __shared__ _Float16 Vs[64][76];    // V^T tile [d][j]   9.5 KB
    __shared__ _Float16 Ps[256][76];   // P tile   [i][j]  38.0 KB

    const int t = threadIdx.x, lane = t & 63, w = t >> 6;
    const int quad = lane >> 4, low = lane & 15;
    const int q0 = blockIdx.x * 256;
    const int b = blockIdx.y >> 4, h = blockIdx.y & 15;
    const int split = blockIdx.z;

    half8 qf[4][2];
#pragma unroll
    for (int ni = 0; ni < 4; ++ni)
#pragma unroll
        for (int ks = 0; ks < 2; ++ks)
            qf[ni][ks] = *(const half8*)(qp +
                (size_t)(b * S + q0 + w * 64 + ni * 16 + low) * 1024 +
                h * 64 + ks * 32 + quad * 8);

    floatx4 oa[4][4], ls[4];
    const floatx4 z4 = {0.f, 0.f, 0.f, 0.f};
#pragma unroll
    for (int mi = 0; mi < 4; ++mi) {
        ls[mi] = z4;
#pragma unroll
        for (int nd = 0; nd < 4; ++nd) oa[mi][nd] = z4;
    }

    const _Float16* kbase = kk + (size_t)(b * S) * 1024 + h * 64;
    const _Float16* vbase = vt + (size_t)(b * 16 + h) * 64 * 2048;

    const int jbeg = split * 1024, jend = jbeg + 1024;
    for (int j0 = jbeg; j0 < jend; j0 += 64) {
        __syncthreads();
#pragma unroll
        for (int p = 0; p < 2; ++p) {
            int c = p * 256 + t;
            int r = c >> 3, o8 = (c & 7) * 8;
            *(half8*)(&Ks[r][o8]) = *(const half8*)(kbase + (size_t)(j0 + r) * 1024 + o8);
            *(half8*)(&Vs[r][o8]) = *(const half8*)(vbase + (size_t)r * 2048 + j0 + o8);
        }
        __syncthreads();

        floatx4 s[4][4];
        const floatx4 i4 = {-3.f, -3.f, -3.f, -3.f};
#pragma unroll
        for (int mj = 0; mj < 4; ++mj)
#pragma unroll
            for (int ni = 0; ni < 4; ++ni) s[mj][ni] = i4;
#pragma unroll
        for (int ks = 0; ks < 2; ++ks) {
            half8 af[4];
#pragma unroll
            for (int mj = 0; mj < 4; ++mj)
                af[mj] = *(const half8*)(&Ks[mj * 16 + low][ks * 32 + quad * 8]);
#pragma unroll
            for (int mj = 0; mj < 4; ++mj)
#pragma unroll
                for (int ni = 0; ni < 4; ++ni)
                    s[mj][ni] = __builtin_amdgcn_mfma_f32_16x16x32_f16(af[mj], qf[ni][ks], s[mj][ni], 0, 0, 0);
        }

#pragma unroll
        for (int mj = 0; mj < 4; ++mj)
#pragma unroll
            for (int ni = 0; ni < 4; ++ni) {
                floatx4 pv;
#pragma unroll
                for (int r = 0; r < 4; ++r) pv[r] = __expf(s[mj][ni][r]);
                ls[ni] += pv;
                half4 ph;
#pragma unroll
                for (int r = 0; r < 4; ++r) ph[r] = (_Float16)pv[r];
                *(half4*)(&Ps[w * 64 + ni * 16 + low][mj * 16 + quad * 4]) = ph;
            }

#pragma unroll
        for (int ks = 0; ks < 2; ++ks) {
            half8 pf[4], vf[4];
#pragma unroll
            for (int mi = 0; mi < 4; ++mi)
                pf[mi] = *(const half8*)(&Ps[w * 64 + mi * 16 + low][ks * 32 + quad * 8]);
#pragma unroll
            for (int nd = 0; nd < 4; ++nd)
                vf[nd] = *(const half8*)(&Vs[nd * 16 + low][ks * 32 + quad * 8]);
#pragma unroll
            for (int mi = 0; mi < 4; ++mi)
#pragma unroll
                for (int nd = 0; nd < 4; ++nd)
                    oa[mi][nd] = __builtin_amdgcn_mfma_f32_16x16x32_f16(pf[mi], vf[nd], oa[mi][nd], 0, 0, 0);
        }
    }

#pragma unroll
    for (int ni = 0; ni < 4; ++ni) {
        float l = ls[ni][0] + ls[ni][1] + ls[ni][2] + ls[ni][3];
        l += __shfl_xor(l, 16);
        l += __shfl_xor(l, 32);
        if (quad == 0)
            lp[split * 65536 + (b * 16 + h) * 2048 + q0 + w * 64 + ni * 16 + low] = l;
    }
    _Float16* op = split ? Op1 : Op0;
#pragma unroll
    for (int mi = 0; mi < 4; ++mi)
#pragma unroll
        for (int nd = 0; nd < 4; ++nd)
#pragma unroll
            for (int r = 0; r < 4; ++r)
                op[(size_t)(b * S + q0 + w * 64 + mi * 16 + quad * 4 + r) * 1024 +
                   h * 64 + nd * 16 + low] = (_Float16)oa[mi][nd][r];
}

// ---------------- combine: att = (O0+O1)/(l0+l1) ----------------
__global__ __launch_bounds__(256) void attn_combine(
    const _Float16* __restrict__ O0, const _Float16* __restrict__ O1,
    const float* __restrict__ lp, _Float16* __restrict__ att)
{
    size_t idx = ((size_t)blockIdx.x * 256 + threadIdx.x) * 8;
    int row = (int)(idx >> 10), c = (int)(idx & 1023);
    int b = row >> 11, qq = row & 2047, h = c >> 6;
    int li = (b * 16 + h) * 2048 + qq;
    float inv = 1.f / (lp[li] + lp[65536 + li]);
    half8 a = *(const half8*)(O0 + idx);
    half8 bb = *(const half8*)(O1 + idx);
    half8 o;
#pragma unroll
    for (int r = 0; r < 8; ++r)
        o[r] = (_Float16)(((float)a[r] + (float)bb[r]) * inv);
    *(half8*)(att + idx) = o;
}

extern "C" void kernel_launch(void* const* d_in, const int* in_sizes, int n_in,
                              void* d_out, int out_size, void* d_ws, size_t ws_size,
                              hipStream_t stream) {
    const float* x  = (const float*)d_in[0];
    const float* Wq = (const float*)d_in[1];
    const float* bq = (const float*)d_in[2];
    const float* Wl = (const float*)d_in[3];
    const float* bl = (const float*)d_in[4];
    const float* Wk = (const float*)d_in[5];
    const float* bk = (const float*)d_in[6];
    const float* Wv = (const float*)d_in[7];
    const float* bv = (const float*)d_in[8];
    const float* Wo = (const float*)d_in[9];
    const float* bo = (const float*)d_in[10];
    float* out = (float*)d_out;

    // workspace carve-up (halfs), ~49.9 MB
    _Float16* p   = (_Float16*)d_ws;
    _Float16* xh  = p; p += 4194304;   // x f16; dead after GEMM1 -> Opart[1]
    _Float16* qh  = p; p += 4194304;   // q' (pre-scaled by 0.125)
    _Float16* kh  = p; p += 4194304;   // k; dead after attn -> combined att
    _Float16* vtb = p; p += 4194304;   // vt [32][64][2048]
    _Float16* ah  = p; p += 4194304;   // Opart[0]
    _Float16* lat = p; p += 1048576;   // lat; dead after GEMM2 -> lp (f32)
    _Float16* Bt1 = p; p += 1310720;
    _Float16* Bt2 = p; p += 524288;
    _Float16* Wot = p; p += 1048576;

    prep<<<dim3(32, 32, 6), 256, 0, stream>>>(x, Wq, Wl, Wk, Wv, Wo, xh, Bt1, Bt2, Wot);

    gemm_fused<0><<<dim3(20, 32), 256, 0, stream>>>(
        xh, Bt1, bq, bl, qh, lat, 1280, 1024);
    gemm_fused<1><<<dim3(32, 32), 256, 0, stream>>>(
        lat, Bt2, bk, bv, kh, vtb, 2048, 256);
    mla_attn<<<dim3(8, 32, 2), 256, 0, stream>>>(qh, kh, vtb, ah, xh, (float*)lat);
    attn_combine<<<2048, 256, 0, stream>>>(ah, xh, (const float*)lat, kh);
    gemm_fused<2><<<dim3(16, 32), 256, 0, stream>>>(
        kh, Wot, bo, nullptr, out, nullptr, 1024, 1024);
}